// Round 1
// 401.387 us; speedup vs baseline: 1.8885x; 1.8885x over previous
//
#include <hip/hip_runtime.h>
#include <hip/hip_bf16.h>

#define Bb 2
#define Ss 2048
#define Dd 1024
#define Hh 16

typedef short bf16x8 __attribute__((ext_vector_type(8)));
typedef short bf16x4 __attribute__((ext_vector_type(4)));
typedef float floatx4 __attribute__((ext_vector_type(4)));
typedef unsigned short u16;

__device__ inline void gld16(void* lds, const void* g) {
  __builtin_amdgcn_global_load_lds(
      (const __attribute__((address_space(1))) unsigned int*)g,
      (__attribute__((address_space(3))) unsigned int*)lds, 16, 0, 0);
}

__device__ inline float bf2f(u16 u) {
  unsigned int x = ((unsigned int)u) << 16;
  float f; __builtin_memcpy(&f, &x, 4); return f;
}
__device__ inline u16 f2bf(float f) {
  unsigned int x; __builtin_memcpy(&x, &f, 4);
  x = (x + 0x7fff + ((x >> 16) & 1)) >> 16;   // RNE
  return (u16)x;
}

// ---------------- dtype sniffer: finite bf16 data never has exponent 0xFF;
// f32 data read as u16 pairs has ~1/256 exponent-0xFF in the mantissa half.
__global__ void sniff(const unsigned int* __restrict__ x, unsigned int* __restrict__ flag,
                      int nwords) {
  __shared__ int cnt;
  if (threadIdx.x == 0) cnt = 0;
  __syncthreads();
  int local = 0;
  for (int i = threadIdx.x; i < nwords; i += blockDim.x) {
    unsigned int wd = x[i];
    if (((wd >> 7)  & 0xFFu) == 0xFFu) local++;   // low-half bf16 exponent
    if (((wd >> 23) & 0xFFu) == 0xFFu) local++;   // high-half bf16 / f32 exponent
  }
  atomicAdd(&cnt, local);
  __syncthreads();
  if (threadIdx.x == 0) *flag = (cnt >= 64) ? 1u : 0u;
}

// ---------------- normalize any input tensor to bf16 in ws.
__global__ __launch_bounds__(256) void convert(const unsigned int* __restrict__ flag,
                                               const void* __restrict__ src,
                                               u16* __restrict__ dst, int n) {
  int i = (blockIdx.x * 256 + threadIdx.x) * 8;
  if (i >= n) return;
  bf16x8 v;
  if (*flag) {
    const float* s = (const float*)src;
#pragma unroll
    for (int j = 0; j < 8; j++) v[j] = (short)f2bf(s[i + j]);
  } else {
    v = *(const bf16x8*)((const u16*)src + i);
  }
  *(bf16x8*)(dst + i) = v;
}

// ---------------- GEMM: C = A(MxK) * W^T, W stored (N,K) row-major.
// m97 structure: 128x128 tile, BK=32, global_load_lds width=16.
// vtrans: for blockIdx.z==2 (the V projection) write C transposed per head:
// Vt[b][h][dl][s] (bf16), so attn can read V^T rows directly.
__global__ __launch_bounds__(256) void gemm_bt(
    const u16* __restrict__ A,
    const u16* __restrict__ W0, const u16* __restrict__ W1, const u16* __restrict__ W2,
    void* __restrict__ C0, void* __restrict__ C1, void* __restrict__ C2,
    int M, int N, int K, const unsigned int* __restrict__ flag, int outMode, int vtrans)
{
  const u16* W; void* C;
  if (blockIdx.z == 0)      { W = W0; C = C0; }
  else if (blockIdx.z == 1) { W = W1; C = C1; }
  else                      { W = W2; C = C2; }

  __shared__ __align__(16) u16 sA[128*32];
  __shared__ __align__(16) u16 sB[128*32];

  const int tid  = threadIdx.x;
  const int lane = tid & 63;
  const int w    = tid >> 6;
  const int wm = w >> 1, wn = w & 1;
  const int col = lane & 15, quad = lane >> 4;
  const int bm = blockIdx.y, bn = blockIdx.x;

  floatx4 acc[4][4] = {};

  const int c0 = tid, c1 = tid + 256;
  const size_t aOff0 = (size_t)(bm*128 + (c0 >> 2))*K + (c0 & 3)*8;
  const size_t aOff1 = (size_t)(bm*128 + (c1 >> 2))*K + (c1 & 3)*8;
  const size_t bOff0 = (size_t)(bn*128 + (c0 >> 2))*K + (c0 & 3)*8;
  const size_t bOff1 = (size_t)(bn*128 + (c1 >> 2))*K + (c1 & 3)*8;

  for (int kk = 0; kk < K; kk += 32) {
    gld16(&sA[c0*8], A + aOff0 + kk);
    gld16(&sA[c1*8], A + aOff1 + kk);
    gld16(&sB[c0*8], W + bOff0 + kk);
    gld16(&sB[c1*8], W + bOff1 + kk);
    __syncthreads();
    bf16x8 af[4], bfr[4];
#pragma unroll
    for (int i = 0; i < 4; i++)
      af[i] = *(const bf16x8*)&sA[(wm*64 + i*16 + col)*32 + quad*8];
#pragma unroll
    for (int j = 0; j < 4; j++)
      bfr[j] = *(const bf16x8*)&sB[(wn*64 + j*16 + col)*32 + quad*8];
#pragma unroll
    for (int i = 0; i < 4; i++)
#pragma unroll
      for (int j = 0; j < 4; j++)
        acc[i][j] = __builtin_amdgcn_mfma_f32_16x16x32_bf16(af[i], bfr[j], acc[i][j], 0, 0, 0);
    __syncthreads();
  }

  if (vtrans && blockIdx.z == 2) {
    // Transposed epilogue: d = gcol (head h = d>>6, dl = d&63), s = grow&2047,
    // b = grow>>11. Four consecutive rows (r) are s-contiguous -> bf16x4 store.
    u16* Ct = (u16*)C;
#pragma unroll
    for (int i = 0; i < 4; i++)
#pragma unroll
      for (int j = 0; j < 4; j++) {
        int d = bn*128 + wn*64 + j*16 + col;
        int g = bm*128 + wm*64 + i*16 + quad*4;
        int hh = d >> 6, dl = d & 63;
        int bb = g >> 11, s = g & (Ss - 1);
        bf16x4 pk;
#pragma unroll
        for (int r = 0; r < 4; r++) pk[r] = (short)f2bf(acc[i][j][r]);
        *(bf16x4*)&Ct[((size_t)(bb*Hh + hh)*64 + dl)*Ss + s] = pk;
      }
  } else {
    const bool f32o = outMode && (*flag != 0u);
#pragma unroll
    for (int i = 0; i < 4; i++)
#pragma unroll
      for (int j = 0; j < 4; j++)
#pragma unroll
        for (int r = 0; r < 4; r++) {
          int grow = bm*128 + wm*64 + i*16 + quad*4 + r;
          int gcol = bn*128 + wn*64 + j*16 + col;
          size_t idx = (size_t)grow*N + gcol;
          float v = acc[i][j][r];
          if (f32o) ((float*)C)[idx] = v;
          else      ((u16*)C)[idx]   = f2bf(v);
        }
  }
}

// ---------------- RMSNorm (per 64-elem head) + RoPE, in place on Q and K.
__global__ __launch_bounds__(256) void rmsrope(u16* __restrict__ Q, u16* __restrict__ Kv) {
  const int lane = threadIdx.x & 63;
  const int g = blockIdx.x * 4 + (threadIdx.x >> 6);   // (b*S+s)*H + h
  u16* p = blockIdx.y ? Kv : Q;
  const size_t off = (size_t)g*64 + lane;
  float x = bf2f(p[off]);
  float ss = x*x;
#pragma unroll
  for (int o = 32; o >= 1; o >>= 1) ss += __shfl_xor(ss, o, 64);
  float rn = rsqrtf(ss*(1.0f/64.0f) + 1e-6f);
  float xn = x*rn;
  const int i = lane & 31;
  float c = 1.0f, sn = 0.0f;
  if (i < 16) {
    float freq = exp2f((-10.0f/15.0f) * (float)i);    // (1/1024)^(i/15)
    float th = (float)((g >> 4) & (Ss - 1)) * freq;   // s = (g/H) % S
    c = cosf(th); sn = sinf(th);
  }
  float part = __shfl_xor(xn, 32, 64);
  float y = (lane < 32) ? (xn*c + part*sn) : (xn*c - part*sn);
  p[off] = f2bf(y);
}

// ---------------- Causal flash attention. Block = 4 waves = 64 Q rows of one (b,h).
// QK^T via MFMA (unchanged); PV now via MFMA: P round-trips LDS as bf16 in
// A-fragment layout, V^T rows (pre-transposed by the V-GEMM epilogue) staged
// with global_load_lds into linear [64][32] LDS and read as B-fragments.
// Online-softmax state (mi/li/alpha) stays fully in registers: the O
// accumulator row mapping (quad*4+r) equals the score row mapping.
__global__ __launch_bounds__(256) void attn(
    const u16* __restrict__ Q, const u16* __restrict__ Kv,
    const u16* __restrict__ Vt, u16* __restrict__ O)
{
  __shared__ __align__(16) u16 sK[32*72];      // K tile [t][dh], +8 pad
  __shared__ __align__(16) u16 sV[64*32];      // V^T tile [d][t], linear (gld16 dest)
  __shared__ __align__(16) u16 sP[4][16*40];   // per-wave P [q][t], stride 40

  const int tid  = threadIdx.x;
  const int lane = tid & 63;
  const int w    = tid >> 6;
  const int col = lane & 15, quad = lane >> 4;
  const int qt = 31 - blockIdx.x;              // heavy tiles first
  const int bh = blockIdx.y;
  const int b = bh >> 4, h = bh & 15;
  const int q0 = qt * 64;
  const size_t base  = (size_t)b*Ss*Dd + (size_t)h*64;
  const size_t vbase = (size_t)bh*64*Ss;

  bf16x8 qf0, qf1;
  {
    const size_t qoff = base + (size_t)(q0 + w*16 + col)*Dd + quad*8;
    qf0 = *(const bf16x8*)(Q + qoff);
    qf1 = *(const bf16x8*)(Q + qoff + 32);
  }

  floatx4 oacc[4] = {};                        // [db][r] : rows quad*4+r, cols db*16+col
  float mi[4], li[4];
#pragma unroll
  for (int r = 0; r < 4; r++) { mi[r] = -1e30f; li[r] = 0.0f; }

  const int nkt  = qt*2 + 2;
  const int wmax = q0 + w*16 + 15;
  const int kr = tid >> 3, kc8 = tid & 7;
  const u16* Vh = Vt + vbase + (size_t)(tid >> 2)*Ss + (tid & 3)*8;

  for (int kt = 0; kt < nkt; kt++) {
    const int t0 = kt*32;
    __syncthreads();
    *(bf16x8*)&sK[kr*72 + kc8*8] =
        *(const bf16x8*)(Kv + base + (size_t)(t0 + kr)*Dd + kc8*8);
    gld16(&sV[tid*8], Vh + t0);                // [d=tid>>2][t-chunk=tid&3]
    __syncthreads();
    if (t0 <= wmax) {
      floatx4 sc0 = {0.f,0.f,0.f,0.f}, sc1 = {0.f,0.f,0.f,0.f};
      bf16x8 k00 = *(const bf16x8*)&sK[col*72 + quad*8];
      bf16x8 k01 = *(const bf16x8*)&sK[col*72 + 32 + quad*8];
      bf16x8 k10 = *(const bf16x8*)&sK[(16+col)*72 + quad*8];
      bf16x8 k11 = *(const bf16x8*)&sK[(16+col)*72 + 32 + quad*8];
      sc0 = __builtin_amdgcn_mfma_f32_16x16x32_bf16(qf0, k00, sc0, 0,0,0);
      sc0 = __builtin_amdgcn_mfma_f32_16x16x32_bf16(qf1, k01, sc0, 0,0,0);
      sc1 = __builtin_amdgcn_mfma_f32_16x16x32_bf16(qf0, k10, sc1, 0,0,0);
      sc1 = __builtin_amdgcn_mfma_f32_16x16x32_bf16(qf1, k11, sc1, 0,0,0);
      float alr[4];
#pragma unroll
      for (int r = 0; r < 4; r++) {
        const int qr = q0 + w*16 + quad*4 + r;
        float s0 = sc0[r]*0.125f;              // 1/sqrt(64)
        float s1 = sc1[r]*0.125f;
        if (t0 + col > qr)      s0 = -1e30f;   // finite mask: no infs anywhere
        if (t0 + 16 + col > qr) s1 = -1e30f;
        float mx = fmaxf(s0, s1);
        mx = fmaxf(mx, __shfl_xor(mx, 1, 64));
        mx = fmaxf(mx, __shfl_xor(mx, 2, 64));
        mx = fmaxf(mx, __shfl_xor(mx, 4, 64));
        mx = fmaxf(mx, __shfl_xor(mx, 8, 64));
        float mn = fmaxf(mi[r], mx);
        float al = exp2f((mi[r] - mn)*1.44269504f);
        float p0 = exp2f((s0 - mn)*1.44269504f);
        float p1 = exp2f((s1 - mn)*1.44269504f);
        u16 h0 = f2bf(p0), h1 = f2bf(p1);
        sP[w][(quad*4 + r)*40 + col]      = h0;
        sP[w][(quad*4 + r)*40 + 16 + col] = h1;
        // li from the ROUNDED p so normalization matches the bf16 PV numerator.
        float ps = bf2f(h0) + bf2f(h1);
        ps += __shfl_xor(ps, 1, 64);
        ps += __shfl_xor(ps, 2, 64);
        ps += __shfl_xor(ps, 4, 64);
        ps += __shfl_xor(ps, 8, 64);
        li[r] = li[r]*al + ps;
        mi[r] = mn;
        alr[r] = al;
      }
#pragma unroll
      for (int db = 0; db < 4; db++)
#pragma unroll
        for (int r = 0; r < 4; r++) oacc[db][r] *= alr[r];
      // Same-wave LDS write->read: DS pipe is in-order per wave.
      bf16x8 pa = *(const bf16x8*)&sP[w][col*40 + quad*8];   // A-frag: P[col][quad*8+j]
#pragma unroll
      for (int db = 0; db < 4; db++) {
        bf16x8 vb = *(const bf16x8*)&sV[(db*16 + col)*32 + quad*8]; // B-frag: V^T[d][t]
        oacc[db] = __builtin_amdgcn_mfma_f32_16x16x32_bf16(pa, vb, oacc[db], 0,0,0);
      }
    }
  }
  float inv[4];
#pragma unroll
  for (int r = 0; r < 4; r++) inv[r] = 1.0f / li[r];
#pragma unroll
  for (int db = 0; db < 4; db++)
#pragma unroll
    for (int r = 0; r < 4; r++)
      O[base + (size_t)(q0 + w*16 + quad*4 + r)*Dd + db*16 + col] =
          f2bf(oacc[db][r] * inv[r]);
}

extern "C" void kernel_launch(void* const* d_in, const int* in_sizes, int n_in,
                              void* d_out, int out_size, void* d_ws, size_t ws_size,
                              hipStream_t stream) {
  const void* x  = d_in[0];
  const void* wq = d_in[1];
  const void* wk = d_in[2];
  const void* wv = d_in[3];
  const void* wo = d_in[4];
  // d_in[5] = mask: causal tril, hardcoded in attn kernel.

  const size_t T  = (size_t)Bb*Ss*Dd;   // 4,194,304
  const size_t WN = (size_t)Dd*Dd;      // 1,048,576

  char* ws = (char*)d_ws;
  unsigned int* flag = (unsigned int*)ws;
  u16* xb  = (u16*)(ws + 256);
  u16* wqb = xb  + T;
  u16* wkb = wqb + WN;
  u16* wvb = wkb + WN;
  u16* wob = wvb + WN;
  u16* Qb  = wob + WN;
  u16* Kb  = Qb + T;
  u16* Vb  = Kb + T;                    // holds V^T per head: [b][h][64][S]
  u16* AO  = Vb + T;                    // total ws use ~48.25 MB

  sniff<<<1, 1024, 0, stream>>>((const unsigned int*)x, flag, 65536);
  convert<<<dim3((int)(T/2048)),  256, 0, stream>>>(flag, x,  xb,  (int)T);
  convert<<<dim3((int)(WN/2048)), 256, 0, stream>>>(flag, wq, wqb, (int)WN);
  convert<<<dim3((int)(WN/2048)), 256, 0, stream>>>(flag, wk, wkb, (int)WN);
  convert<<<dim3((int)(WN/2048)), 256, 0, stream>>>(flag, wv, wvb, (int)WN);
  convert<<<dim3((int)(WN/2048)), 256, 0, stream>>>(flag, wo, wob, (int)WN);

  gemm_bt<<<dim3(8, 32, 3), 256, 0, stream>>>(xb, wqb, wkb, wvb, Qb, Kb, Vb,
                                              4096, 1024, 1024, flag, 0, 1);
  rmsrope<<<dim3((Bb*Ss*Hh)/4, 2), 256, 0, stream>>>(Qb, Kb);
  attn<<<dim3(32, Bb*Hh), 256, 0, stream>>>(Qb, Kb, Vb, AO);
  gemm_bt<<<dim3(8, 32, 1), 256, 0, stream>>>(AO, wob, wob, wob, d_out, d_out, d_out,
                                              4096, 1024, 1024, flag, 1, 0);
}

// Round 3
// 303.252 us; speedup vs baseline: 2.4996x; 1.3236x over previous
//
#include <hip/hip_runtime.h>
#include <hip/hip_bf16.h>

#define Bb 2
#define Ss 2048
#define Dd 1024
#define Hh 16

typedef short bf16x8 __attribute__((ext_vector_type(8)));
typedef short bf16x4 __attribute__((ext_vector_type(4)));
typedef float floatx4 __attribute__((ext_vector_type(4)));
typedef unsigned short u16;

__device__ inline void gld16(void* lds, const void* g) {
  __builtin_amdgcn_global_load_lds(
      (const __attribute__((address_space(1))) unsigned int*)g,
      (__attribute__((address_space(3))) unsigned int*)lds, 16, 0, 0);
}

__device__ inline float bf2f(u16 u) {
  unsigned int x = ((unsigned int)u) << 16;
  float f; __builtin_memcpy(&f, &x, 4); return f;
}
__device__ inline u16 f2bf(float f) {
  unsigned int x; __builtin_memcpy(&x, &f, 4);
  x = (x + 0x7fff + ((x >> 16) & 1)) >> 16;   // RNE
  return (u16)x;
}
__device__ inline float u2f(unsigned int x) {
  float f; __builtin_memcpy(&f, &x, 4); return f;
}
// HW packed f32->bf16 (RNE), no builtin on gfx950 -> inline asm.
__device__ inline unsigned int cvtpk(float lo, float hi) {
  unsigned int r;
  asm("v_cvt_pk_bf16_f32 %0, %1, %2" : "=v"(r) : "v"(lo), "v"(hi));
  return r;
}

// ---------------- dtype sniffer: finite bf16 data never has exponent 0xFF;
// f32 data read as u16 pairs has ~1/256 exponent-0xFF in the mantissa half.
__global__ void sniff(const unsigned int* __restrict__ x, unsigned int* __restrict__ flag,
                      int nwords) {
  __shared__ int cnt;
  if (threadIdx.x == 0) cnt = 0;
  __syncthreads();
  int local = 0;
  for (int i = threadIdx.x; i < nwords; i += blockDim.x) {
    unsigned int wd = x[i];
    if (((wd >> 7)  & 0xFFu) == 0xFFu) local++;
    if (((wd >> 23) & 0xFFu) == 0xFFu) local++;
  }
  atomicAdd(&cnt, local);
  __syncthreads();
  if (threadIdx.x == 0) *flag = (cnt >= 64) ? 1u : 0u;
}

// ---------------- normalize any input tensor to bf16 in ws.
__global__ __launch_bounds__(256) void convert(const unsigned int* __restrict__ flag,
                                               const void* __restrict__ src,
                                               u16* __restrict__ dst, int n) {
  int i = (blockIdx.x * 256 + threadIdx.x) * 8;
  if (i >= n) return;
  bf16x8 v;
  if (*flag) {
    const float* s = (const float*)src;
#pragma unroll
    for (int j = 0; j < 8; j++) v[j] = (short)f2bf(s[i + j]);
  } else {
    v = *(const bf16x8*)((const u16*)src + i);
  }
  *(bf16x8*)(dst + i) = v;
}

// ---------------- GEMM: C = A(MxK) * W^T, W stored (N,K) row-major.
// m97 structure: 128x128 tile, BK=32, global_load_lds width=16.
// vtrans: for blockIdx.z==2 (the V projection) write C transposed per head:
// Vt[b][h][dl][s] (bf16), so attn can read V^T rows directly.
__global__ __launch_bounds__(256) void gemm_bt(
    const u16* __restrict__ A,
    const u16* __restrict__ W0, const u16* __restrict__ W1, const u16* __restrict__ W2,
    void* __restrict__ C0, void* __restrict__ C1, void* __restrict__ C2,
    int M, int N, int K, const unsigned int* __restrict__ flag, int outMode, int vtrans)
{
  const u16* W; void* C;
  if (blockIdx.z == 0)      { W = W0; C = C0; }
  else if (blockIdx.z == 1) { W = W1; C = C1; }
  else                      { W = W2; C = C2; }

  __shared__ __align__(16) u16 sA[128*32];
  __shared__ __align__(16) u16 sB[128*32];

  const int tid  = threadIdx.x;
  const int lane = tid & 63;
  const int w    = tid >> 6;
  const int wm = w >> 1, wn = w & 1;
  const int col = lane & 15, quad = lane >> 4;
  const int bm = blockIdx.y, bn = blockIdx.x;

  floatx4 acc[4][4] = {};

  const int c0 = tid, c1 = tid + 256;
  const size_t aOff0 = (size_t)(bm*128 + (c0 >> 2))*K + (c0 & 3)*8;
  const size_t aOff1 = (size_t)(bm*128 + (c1 >> 2))*K + (c1 & 3)*8;
  const size_t bOff0 = (size_t)(bn*128 + (c0 >> 2))*K + (c0 & 3)*8;
  const size_t bOff1 = (size_t)(bn*128 + (c1 >> 2))*K + (c1 & 3)*8;

  for (int kk = 0; kk < K; kk += 32) {
    gld16(&sA[c0*8], A + aOff0 + kk);
    gld16(&sA[c1*8], A + aOff1 + kk);
    gld16(&sB[c0*8], W + bOff0 + kk);
    gld16(&sB[c1*8], W + bOff1 + kk);
    __syncthreads();
    bf16x8 af[4], bfr[4];
#pragma unroll
    for (int i = 0; i < 4; i++)
      af[i] = *(const bf16x8*)&sA[(wm*64 + i*16 + col)*32 + quad*8];
#pragma unroll
    for (int j = 0; j < 4; j++)
      bfr[j] = *(const bf16x8*)&sB[(wn*64 + j*16 + col)*32 + quad*8];
#pragma unroll
    for (int i = 0; i < 4; i++)
#pragma unroll
      for (int j = 0; j < 4; j++)
        acc[i][j] = __builtin_amdgcn_mfma_f32_16x16x32_bf16(af[i], bfr[j], acc[i][j], 0, 0, 0);
    __syncthreads();
  }

  if (vtrans && blockIdx.z == 2) {
    u16* Ct = (u16*)C;
#pragma unroll
    for (int i = 0; i < 4; i++)
#pragma unroll
      for (int j = 0; j < 4; j++) {
        int d = bn*128 + wn*64 + j*16 + col;
        int g = bm*128 + wm*64 + i*16 + quad*4;
        int hh = d >> 6, dl = d & 63;
        int bb = g >> 11, s = g & (Ss - 1);
        bf16x4 pk;
#pragma unroll
        for (int r = 0; r < 4; r++) pk[r] = (short)f2bf(acc[i][j][r]);
        *(bf16x4*)&Ct[((size_t)(bb*Hh + hh)*64 + dl)*Ss + s] = pk;
      }
  } else {
    const bool f32o = outMode && (*flag != 0u);
#pragma unroll
    for (int i = 0; i < 4; i++)
#pragma unroll
      for (int j = 0; j < 4; j++)
#pragma unroll
        for (int r = 0; r < 4; r++) {
          int grow = bm*128 + wm*64 + i*16 + quad*4 + r;
          int gcol = bn*128 + wn*64 + j*16 + col;
          size_t idx = (size_t)grow*N + gcol;
          float v = acc[i][j][r];
          if (f32o) ((float*)C)[idx] = v;
          else      ((u16*)C)[idx]   = f2bf(v);
        }
  }
}

// ---------------- RMSNorm (per 64-elem head) + RoPE, in place on Q and K.
__global__ __launch_bounds__(256) void rmsrope(u16* __restrict__ Q, u16* __restrict__ Kv) {
  const int lane = threadIdx.x & 63;
  const int g = blockIdx.x * 4 + (threadIdx.x >> 6);   // (b*S+s)*H + h
  u16* p = blockIdx.y ? Kv : Q;
  const size_t off = (size_t)g*64 + lane;
  float x = bf2f(p[off]);
  float ss = x*x;
#pragma unroll
  for (int o = 32; o >= 1; o >>= 1) ss += __shfl_xor(ss, o, 64);
  float rn = rsqrtf(ss*(1.0f/64.0f) + 1e-6f);
  float xn = x*rn;
  const int i = lane & 31;
  float c = 1.0f, sn = 0.0f;
  if (i < 16) {
    float freq = exp2f((-10.0f/15.0f) * (float)i);    // (1/1024)^(i/15)
    float th = (float)((g >> 4) & (Ss - 1)) * freq;   // s = (g/H) % S
    c = cosf(th); sn = sinf(th);
  }
  float part = __shfl_xor(xn, 32, 64);
  float y = (lane < 32) ? (xn*c + part*sn) : (xn*c - part*sn);
  p[off] = f2bf(y);
}

// ---------------- Causal flash attention, balanced + double-buffered.
// Grid (16, B*H): block bx handles q-tiles {bx, 31-bx} (64 rows each) -> every
// block runs exactly 33 64-t tile iterations (uniform work). K/V tiles are
// double-buffered: loads for tile k+1 issue before compute of tile k (latency
// hidden under MFMA+softmax); one barrier per iteration. Online softmax uses
// defer-max (THR=8): oacc rescale skipped unless the running max grows.
__global__ __launch_bounds__(256) void attn(
    const u16* __restrict__ Q, const u16* __restrict__ Kv,
    const u16* __restrict__ Vt, u16* __restrict__ O)
{
  __shared__ __align__(16) u16 sK[2][64*72];      // [buf][t][dh], stride 72
  __shared__ __align__(16) u16 sV[2][2][64*32];   // [buf][ts][d][t], gld16-linear
  __shared__ __align__(16) u16 sP[4][16*72];      // per-wave P [q][t], stride 72

  const int tid  = threadIdx.x;
  const int lane = tid & 63;
  const int w    = tid >> 6;
  const int col = lane & 15, quad = lane >> 4;
  const int bh = blockIdx.y;
  const int b = bh >> 4, h = bh & 15;
  const size_t base  = (size_t)b*Ss*Dd + (size_t)h*64;
  const size_t vbase = (size_t)bh*64*Ss;

  const int krow = tid >> 2;              // K stage: row 0..63
  const int kch  = (tid & 3) * 2;         // 16B-chunk col {0,2,4,6}
  const u16* Vh = Vt + vbase + (size_t)(tid >> 2)*Ss + (tid & 3)*8;
  u16* sPw = &sP[w][0];
  const float L2E = 1.44269504f;

  for (int seg = 0; seg < 2; seg++) {
    const int qt = seg ? 31 - (int)blockIdx.x : (int)blockIdx.x;
    const int q0 = qt * 64;
    const int nk = qt + 1;                // 64-t tiles
    const int qmin = q0 + w*16;

    bf16x8 qf0, qf1;
    {
      const size_t qoff = base + (size_t)(q0 + w*16 + col)*Dd + quad*8;
      qf0 = *(const bf16x8*)(Q + qoff);
      qf1 = *(const bf16x8*)(Q + qoff + 32);
    }
    floatx4 oacc[4] = {};
    float mi[4], li[4];
#pragma unroll
    for (int r = 0; r < 4; r++) { mi[r] = -1e30f; li[r] = 0.0f; }

    // -------- prologue: stage tile 0 into buffer 0
    {
      const u16* kg = Kv + base + (size_t)krow*Dd + kch*8;
      bf16x8 ka = *(const bf16x8*)kg;
      bf16x8 kb = *(const bf16x8*)(kg + 8);
      __syncthreads();                    // prior readers of LDS done
      gld16(&sV[0][0][tid*8], Vh);
      gld16(&sV[0][1][tid*8], Vh + 32);
      *(bf16x8*)&sK[0][krow*72 + kch*8]     = ka;
      *(bf16x8*)&sK[0][krow*72 + kch*8 + 8] = kb;
      __syncthreads();                    // drains gld16 + ds_writes
    }

    for (int kt = 0; kt < nk; kt++) {
      const int t0 = kt*64;
      const int cur = kt & 1, nxt = cur ^ 1;
      const bool more = (kt + 1 < nk);
      bf16x8 ka, kb;
      if (more) {                         // issue next-tile loads early
        const u16* kg = Kv + base + (size_t)(t0 + 64 + krow)*Dd + kch*8;
        ka = *(const bf16x8*)kg;
        kb = *(const bf16x8*)(kg + 8);
        gld16(&sV[nxt][0][tid*8], Vh + t0 + 64);
        gld16(&sV[nxt][1][tid*8], Vh + t0 + 96);
      }

      // ---- QK^T (4 t-subtiles x 2 k-halves)
      floatx4 sc[4] = {};
      __builtin_amdgcn_s_setprio(1);
#pragma unroll
      for (int ts = 0; ts < 4; ts++) {
        bf16x8 k0 = *(const bf16x8*)&sK[cur][(ts*16 + col)*72 + quad*8];
        bf16x8 k1 = *(const bf16x8*)&sK[cur][(ts*16 + col)*72 + 32 + quad*8];
        sc[ts] = __builtin_amdgcn_mfma_f32_16x16x32_bf16(qf0, k0, sc[ts], 0,0,0);
        sc[ts] = __builtin_amdgcn_mfma_f32_16x16x32_bf16(qf1, k1, sc[ts], 0,0,0);
      }
      __builtin_amdgcn_s_setprio(0);

      // ---- masked scale + row max (boundary tile only masks)
      const bool boundary = (t0 + 63 > qmin);
      float mxr[4];
      float needmax = 0.0f;
#pragma unroll
      for (int r = 0; r < 4; r++) {
        float s0 = sc[0][r]*0.125f, s1 = sc[1][r]*0.125f;
        float s2 = sc[2][r]*0.125f, s3 = sc[3][r]*0.125f;
        if (boundary) {
          const int qr = q0 + w*16 + quad*4 + r;
          if (t0 +      col > qr) s0 = -1e30f;
          if (t0 + 16 + col > qr) s1 = -1e30f;
          if (t0 + 32 + col > qr) s2 = -1e30f;
          if (t0 + 48 + col > qr) s3 = -1e30f;
        }
        sc[0][r] = s0; sc[1][r] = s1; sc[2][r] = s2; sc[3][r] = s3;
        float mx = fmaxf(fmaxf(s0, s1), fmaxf(s2, s3));
        mx = fmaxf(mx, __shfl_xor(mx, 1, 64));
        mx = fmaxf(mx, __shfl_xor(mx, 2, 64));
        mx = fmaxf(mx, __shfl_xor(mx, 4, 64));
        mx = fmaxf(mx, __shfl_xor(mx, 8, 64));
        mxr[r] = mx;
        needmax = fmaxf(needmax, mx - mi[r]);
      }
      // ---- defer-max: only rescale when the running max grows past THR=8
      if (!__all(needmax <= 8.0f)) {
        float alr[4];
#pragma unroll
        for (int r = 0; r < 4; r++) {
          float mn = fmaxf(mi[r], mxr[r]);
          float al = exp2f((mi[r] - mn)*L2E);
          mi[r] = mn; li[r] *= al; alr[r] = al;
        }
#pragma unroll
        for (int db = 0; db < 4; db++)
#pragma unroll
          for (int r = 0; r < 4; r++) oacc[db][r] *= alr[r];
      }
      // ---- P = exp2(s - mi), pack to bf16 (HW cvt_pk), li from rounded p
#pragma unroll
      for (int r = 0; r < 4; r++) {
        const float nb = -mi[r]*L2E;
        float p0 = exp2f(fmaf(sc[0][r], L2E, nb));
        float p1 = exp2f(fmaf(sc[1][r], L2E, nb));
        float p2 = exp2f(fmaf(sc[2][r], L2E, nb));
        float p3 = exp2f(fmaf(sc[3][r], L2E, nb));
        unsigned int pk01 = cvtpk(p0, p1);
        unsigned int pk23 = cvtpk(p2, p3);
        const int rw = (quad*4 + r)*72;
        sPw[rw + col]      = (u16)pk01;
        sPw[rw + 16 + col] = (u16)(pk01 >> 16);
        sPw[rw + 32 + col] = (u16)pk23;
        sPw[rw + 48 + col] = (u16)(pk23 >> 16);
        float ps = (u2f(pk01 << 16) + u2f(pk01 & 0xffff0000u))
                 + (u2f(pk23 << 16) + u2f(pk23 & 0xffff0000u));
        ps += __shfl_xor(ps, 1, 64);
        ps += __shfl_xor(ps, 2, 64);
        ps += __shfl_xor(ps, 4, 64);
        ps += __shfl_xor(ps, 8, 64);
        li[r] += ps;
      }
      // ---- PV (same-wave LDS write->read: DS pipe in-order per wave)
      bf16x8 pa0 = *(const bf16x8*)&sPw[col*72 + quad*8];
      bf16x8 pa1 = *(const bf16x8*)&sPw[col*72 + 32 + quad*8];
      __builtin_amdgcn_s_setprio(1);
#pragma unroll
      for (int db = 0; db < 4; db++) {
        bf16x8 vb0 = *(const bf16x8*)&sV[cur][0][(db*16 + col)*32 + quad*8];
        bf16x8 vb1 = *(const bf16x8*)&sV[cur][1][(db*16 + col)*32 + quad*8];
        oacc[db] = __builtin_amdgcn_mfma_f32_16x16x32_bf16(pa0, vb0, oacc[db], 0,0,0);
        oacc[db] = __builtin_amdgcn_mfma_f32_16x16x32_bf16(pa1, vb1, oacc[db], 0,0,0);
      }
      __builtin_amdgcn_s_setprio(0);

      if (more) {                         // write next K tile (compiler waits loads)
        *(bf16x8*)&sK[nxt][krow*72 + kch*8]     = ka;
        *(bf16x8*)&sK[nxt][krow*72 + kch*8 + 8] = kb;
      }
      __syncthreads();                    // drains gld16 + ds_writes; flips buffers
    }

    // -------- segment epilogue
    float inv[4];
#pragma unroll
    for (int r = 0; r < 4; r++) inv[r] = 1.0f / li[r];
#pragma unroll
    for (int db = 0; db < 4; db++)
#pragma unroll
      for (int r = 0; r < 4; r++)
        O[base + (size_t)(q0 + w*16 + quad*4 + r)*Dd + db*16 + col] =
            f2bf(oacc[db][r] * inv[r]);
  }
}

extern "C" void kernel_launch(void* const* d_in, const int* in_sizes, int n_in,
                              void* d_out, int out_size, void* d_ws, size_t ws_size,
                              hipStream_t stream) {
  const void* x  = d_in[0];
  const void* wq = d_in[1];
  const void* wk = d_in[2];
  const void* wv = d_in[3];
  const void* wo = d_in[4];
  // d_in[5] = mask: causal tril, hardcoded in attn kernel.

  const size_t T  = (size_t)Bb*Ss*Dd;   // 4,194,304
  const size_t WN = (size_t)Dd*Dd;      // 1,048,576

  char* ws = (char*)d_ws;
  unsigned int* flag = (unsigned int*)ws;
  u16* xb  = (u16*)(ws + 256);
  u16* wqb = xb  + T;
  u16* wkb = wqb + WN;
  u16* wvb = wkb + WN;
  u16* wob = wvb + WN;
  u16* Qb  = wob + WN;
  u16* Kb  = Qb + T;
  u16* Vb  = Kb + T;                    // holds V^T per head: [b][h][64][S]
  u16* AO  = Vb + T;                    // total ws use ~48.25 MB

  sniff<<<1, 1024, 0, stream>>>((const unsigned int*)x, flag, 65536);
  convert<<<dim3((int)(T/2048)),  256, 0, stream>>>(flag, x,  xb,  (int)T);
  convert<<<dim3((int)(WN/2048)), 256, 0, stream>>>(flag, wq, wqb, (int)WN);
  convert<<<dim3((int)(WN/2048)), 256, 0, stream>>>(flag, wk, wkb, (int)WN);
  convert<<<dim3((int)(WN/2048)), 256, 0, stream>>>(flag, wv, wvb, (int)WN);
  convert<<<dim3((int)(WN/2048)), 256, 0, stream>>>(flag, wo, wob, (int)WN);

  gemm_bt<<<dim3(8, 32, 3), 256, 0, stream>>>(xb, wqb, wkb, wvb, Qb, Kb, Vb,
                                              4096, 1024, 1024, flag, 0, 1);
  rmsrope<<<dim3((Bb*Ss*Hh)/4, 2), 256, 0, stream>>>(Qb, Kb);
  attn<<<dim3(16, Bb*Hh), 256, 0, stream>>>(Qb, Kb, Vb, AO);
  gemm_bt<<<dim3(8, 32, 1), 256, 0, stream>>>(AO, wob, wob, wob, d_out, d_out, d_out,
                                              4096, 1024, 1024, flag, 1, 0);
}

// Round 4
// 294.186 us; speedup vs baseline: 2.5766x; 1.0308x over previous
//
#include <hip/hip_runtime.h>
#include <hip/hip_bf16.h>

#define Bb 2
#define Ss 2048
#define Dd 1024
#define Hh 16

typedef short bf16x8 __attribute__((ext_vector_type(8)));
typedef short bf16x4 __attribute__((ext_vector_type(4)));
typedef float floatx4 __attribute__((ext_vector_type(4)));
typedef unsigned short u16;

__device__ inline void gld16(void* lds, const void* g) {
  __builtin_amdgcn_global_load_lds(
      (const __attribute__((address_space(1))) unsigned int*)g,
      (__attribute__((address_space(3))) unsigned int*)lds, 16, 0, 0);
}

__device__ inline float bf2f(u16 u) {
  unsigned int x = ((unsigned int)u) << 16;
  float f; __builtin_memcpy(&f, &x, 4); return f;
}
__device__ inline u16 f2bf(float f) {
  unsigned int x; __builtin_memcpy(&x, &f, 4);
  x = (x + 0x7fff + ((x >> 16) & 1)) >> 16;   // RNE
  return (u16)x;
}
__device__ inline float u2f(unsigned int x) {
  float f; __builtin_memcpy(&f, &x, 4); return f;
}
// HW packed f32->bf16 (RNE), no builtin on gfx950 -> inline asm.
__device__ inline unsigned int cvtpk(float lo, float hi) {
  unsigned int r;
  asm("v_cvt_pk_bf16_f32 %0, %1, %2" : "=v"(r) : "v"(lo), "v"(hi));
  return r;
}

// ---------------- dtype sniffer: finite bf16 data never has exponent 0xFF;
// f32 data read as u16 pairs has ~1/256 exponent-0xFF in the mantissa half.
__global__ void sniff(const unsigned int* __restrict__ x, unsigned int* __restrict__ flag,
                      int nwords) {
  __shared__ int cnt;
  if (threadIdx.x == 0) cnt = 0;
  __syncthreads();
  int local = 0;
  for (int i = threadIdx.x; i < nwords; i += blockDim.x) {
    unsigned int wd = x[i];
    if (((wd >> 7)  & 0xFFu) == 0xFFu) local++;
    if (((wd >> 23) & 0xFFu) == 0xFFu) local++;
  }
  atomicAdd(&cnt, local);
  __syncthreads();
  if (threadIdx.x == 0) *flag = (cnt >= 64) ? 1u : 0u;
}

// ---------------- normalize any input tensor to bf16 in ws.
__global__ __launch_bounds__(256) void convert(const unsigned int* __restrict__ flag,
                                               const void* __restrict__ src,
                                               u16* __restrict__ dst, int n) {
  int i = (blockIdx.x * 256 + threadIdx.x) * 8;
  if (i >= n) return;
  bf16x8 v;
  if (*flag) {
    const float* s = (const float*)src;
#pragma unroll
    for (int j = 0; j < 8; j++) v[j] = (short)f2bf(s[i + j]);
  } else {
    v = *(const bf16x8*)((const u16*)src + i);
  }
  *(bf16x8*)(dst + i) = v;
}

// ---------------- GEMM: C = A(MxK) * W^T, W stored (N,K) row-major.
// m97 structure: 128x128 tile, BK=32, global_load_lds width=16.
// vtrans: for blockIdx.z==2 (the V projection) write C transposed per head:
// Vt[b][h][dl][s] (bf16), so attn can read V^T rows directly.
__global__ __launch_bounds__(256) void gemm_bt(
    const u16* __restrict__ A,
    const u16* __restrict__ W0, const u16* __restrict__ W1, const u16* __restrict__ W2,
    void* __restrict__ C0, void* __restrict__ C1, void* __restrict__ C2,
    int M, int N, int K, const unsigned int* __restrict__ flag, int outMode, int vtrans)
{
  const u16* W; void* C;
  if (blockIdx.z == 0)      { W = W0; C = C0; }
  else if (blockIdx.z == 1) { W = W1; C = C1; }
  else                      { W = W2; C = C2; }

  __shared__ __align__(16) u16 sA[128*32];
  __shared__ __align__(16) u16 sB[128*32];

  const int tid  = threadIdx.x;
  const int lane = tid & 63;
  const int w    = tid >> 6;
  const int wm = w >> 1, wn = w & 1;
  const int col = lane & 15, quad = lane >> 4;
  const int bm = blockIdx.y, bn = blockIdx.x;

  floatx4 acc[4][4] = {};

  const int c0 = tid, c1 = tid + 256;
  const size_t aOff0 = (size_t)(bm*128 + (c0 >> 2))*K + (c0 & 3)*8;
  const size_t aOff1 = (size_t)(bm*128 + (c1 >> 2))*K + (c1 & 3)*8;
  const size_t bOff0 = (size_t)(bn*128 + (c0 >> 2))*K + (c0 & 3)*8;
  const size_t bOff1 = (size_t)(bn*128 + (c1 >> 2))*K + (c1 & 3)*8;

  for (int kk = 0; kk < K; kk += 32) {
    gld16(&sA[c0*8], A + aOff0 + kk);
    gld16(&sA[c1*8], A + aOff1 + kk);
    gld16(&sB[c0*8], W + bOff0 + kk);
    gld16(&sB[c1*8], W + bOff1 + kk);
    __syncthreads();
    bf16x8 af[4], bfr[4];
#pragma unroll
    for (int i = 0; i < 4; i++)
      af[i] = *(const bf16x8*)&sA[(wm*64 + i*16 + col)*32 + quad*8];
#pragma unroll
    for (int j = 0; j < 4; j++)
      bfr[j] = *(const bf16x8*)&sB[(wn*64 + j*16 + col)*32 + quad*8];
#pragma unroll
    for (int i = 0; i < 4; i++)
#pragma unroll
      for (int j = 0; j < 4; j++)
        acc[i][j] = __builtin_amdgcn_mfma_f32_16x16x32_bf16(af[i], bfr[j], acc[i][j], 0, 0, 0);
    __syncthreads();
  }

  if (vtrans && blockIdx.z == 2) {
    u16* Ct = (u16*)C;
#pragma unroll
    for (int i = 0; i < 4; i++)
#pragma unroll
      for (int j = 0; j < 4; j++) {
        int d = bn*128 + wn*64 + j*16 + col;
        int g = bm*128 + wm*64 + i*16 + quad*4;
        int hh = d >> 6, dl = d & 63;
        int bb = g >> 11, s = g & (Ss - 1);
        bf16x4 pk;
#pragma unroll
        for (int r = 0; r < 4; r++) pk[r] = (short)f2bf(acc[i][j][r]);
        *(bf16x4*)&Ct[((size_t)(bb*Hh + hh)*64 + dl)*Ss + s] = pk;
      }
  } else {
    const bool f32o = outMode && (*flag != 0u);
#pragma unroll
    for (int i = 0; i < 4; i++)
#pragma unroll
      for (int j = 0; j < 4; j++)
#pragma unroll
        for (int r = 0; r < 4; r++) {
          int grow = bm*128 + wm*64 + i*16 + quad*4 + r;
          int gcol = bn*128 + wn*64 + j*16 + col;
          size_t idx = (size_t)grow*N + gcol;
          float v = acc[i][j][r];
          if (f32o) ((float*)C)[idx] = v;
          else      ((u16*)C)[idx]   = f2bf(v);
        }
  }
}

// ---------------- RMSNorm (per 64-elem head) + RoPE, in place on Q and K.
// Q additionally pre-scaled by 1/sqrt(DH) = 0.125 (exact in bf16: pow2) so
// the attn kernel's QK^T output is the final score with no per-element mul.
__global__ __launch_bounds__(256) void rmsrope(u16* __restrict__ Q, u16* __restrict__ Kv) {
  const int lane = threadIdx.x & 63;
  const int g = blockIdx.x * 4 + (threadIdx.x >> 6);   // (b*S+s)*H + h
  u16* p = blockIdx.y ? Kv : Q;
  const float qs = blockIdx.y ? 1.0f : 0.125f;
  const size_t off = (size_t)g*64 + lane;
  float x = bf2f(p[off]);
  float ss = x*x;
#pragma unroll
  for (int o = 32; o >= 1; o >>= 1) ss += __shfl_xor(ss, o, 64);
  float rn = rsqrtf(ss*(1.0f/64.0f) + 1e-6f);
  float xn = x*rn;
  const int i = lane & 31;
  float c = 1.0f, sn = 0.0f;
  if (i < 16) {
    float freq = exp2f((-10.0f/15.0f) * (float)i);    // (1/1024)^(i/15)
    float th = (float)((g >> 4) & (Ss - 1)) * freq;   // s = (g/H) % S
    c = cosf(th); sn = sinf(th);
  }
  float part = __shfl_xor(xn, 32, 64);
  float y = (lane < 32) ? (xn*c + part*sn) : (xn*c - part*sn);
  p[off] = f2bf(y * qs);
}

// ---------------- Causal flash attention, heavy-first + double-buffered.
// Grid (32 bh, 32 qy): qt = 31 - blockIdx.y so linear dispatch order is
// descending work (heavy q-tiles start first; light blocks backfill) -> 1024
// blocks, 3 resident/CU (LDS-capped at 44KB). K/V double-buffered with loads
// issued before compute. sV staged via gld16 with a PRE-SWIZZLED global source
// (chunk c^=(d&3)^((d>>2)&3)) so the PV ds_read_b128 is uniform 2-way (free)
// instead of 8-way. Online softmax: defer-max (THR=8) + lane-partial li
// (row-reduced once at epilogue; alpha-rescale is uniform per row so partial
// sums scale linearly).
__global__ __launch_bounds__(256) void attn(
    const u16* __restrict__ Q, const u16* __restrict__ Kv,
    const u16* __restrict__ Vt, u16* __restrict__ O)
{
  __shared__ __align__(16) u16 sK[2][64*72];      // [buf][t][dh], stride 72
  __shared__ __align__(16) u16 sV[2][2][64*32];   // [buf][ts][slot], gld16-linear
  __shared__ __align__(16) u16 sP[4][16*72];      // per-wave P [q][t], stride 72

  const int tid  = threadIdx.x;
  const int lane = tid & 63;
  const int w    = tid >> 6;
  const int col = lane & 15, quad = lane >> 4;
  const int bh = blockIdx.x;
  const int qt = 31 - (int)blockIdx.y;            // heavy-first dispatch order
  const int b = bh >> 4, h = bh & 15;
  const size_t base  = (size_t)b*Ss*Dd + (size_t)h*64;
  const size_t vbase = (size_t)bh*64*Ss;

  const int krow = tid >> 2;              // K stage: row 0..63
  const int kch  = (tid & 3) * 2;         // 16B-chunk col {0,2,4,6}
  // V stage: slot tid holds chunk c' of row d=tid>>2, c' = c^(d&3)^((d>>2)&3).
  const int vrow = tid >> 2;
  const int vcp  = (tid & 3) ^ (vrow & 3) ^ ((vrow >> 2) & 3);
  const u16* Vh = Vt + vbase + (size_t)vrow*Ss + vcp*8;
  const int xorv = quad ^ (col & 3) ^ ((col >> 2) & 3);  // PV read swizzle
  u16* sPw = &sP[w][0];
  const float L2E = 1.44269504f;

  const int q0 = qt * 64;
  const int nk = qt + 1;                  // 64-t tiles
  const int qmin = q0 + w*16;

  bf16x8 qf0, qf1;
  {
    const size_t qoff = base + (size_t)(q0 + w*16 + col)*Dd + quad*8;
    qf0 = *(const bf16x8*)(Q + qoff);
    qf1 = *(const bf16x8*)(Q + qoff + 32);
  }
  floatx4 oacc[4] = {};
  float mi[4], li[4];
#pragma unroll
  for (int r = 0; r < 4; r++) { mi[r] = -1e30f; li[r] = 0.0f; }

  // -------- prologue: stage tile 0 into buffer 0
  {
    const u16* kg = Kv + base + (size_t)krow*Dd + kch*8;
    bf16x8 ka = *(const bf16x8*)kg;
    bf16x8 kb = *(const bf16x8*)(kg + 8);
    gld16(&sV[0][0][tid*8], Vh);
    gld16(&sV[0][1][tid*8], Vh + 32);
    *(bf16x8*)&sK[0][krow*72 + kch*8]     = ka;
    *(bf16x8*)&sK[0][krow*72 + kch*8 + 8] = kb;
    __syncthreads();                      // drains gld16 + ds_writes
  }

  for (int kt = 0; kt < nk; kt++) {
    const int t0 = kt*64;
    const int cur = kt & 1, nxt = cur ^ 1;
    const bool more = (kt + 1 < nk);
    bf16x8 ka, kb;
    if (more) {                           // issue next-tile loads early
      const u16* kg = Kv + base + (size_t)(t0 + 64 + krow)*Dd + kch*8;
      ka = *(const bf16x8*)kg;
      kb = *(const bf16x8*)(kg + 8);
      gld16(&sV[nxt][0][tid*8], Vh + t0 + 64);
      gld16(&sV[nxt][1][tid*8], Vh + t0 + 96);
    }

    // ---- QK^T (4 t-subtiles x 2 k-halves); Q pre-scaled -> sc is the score
    floatx4 sc[4] = {};
    __builtin_amdgcn_s_setprio(1);
#pragma unroll
    for (int ts = 0; ts < 4; ts++) {
      bf16x8 k0 = *(const bf16x8*)&sK[cur][(ts*16 + col)*72 + quad*8];
      bf16x8 k1 = *(const bf16x8*)&sK[cur][(ts*16 + col)*72 + 32 + quad*8];
      sc[ts] = __builtin_amdgcn_mfma_f32_16x16x32_bf16(qf0, k0, sc[ts], 0,0,0);
      sc[ts] = __builtin_amdgcn_mfma_f32_16x16x32_bf16(qf1, k1, sc[ts], 0,0,0);
    }
    __builtin_amdgcn_s_setprio(0);

    // ---- mask (boundary tile only) + row max
    const bool boundary = (t0 + 63 > qmin);
    float mxr[4];
    float needmax = 0.0f;
#pragma unroll
    for (int r = 0; r < 4; r++) {
      if (boundary) {
        const int qr = q0 + w*16 + quad*4 + r;
        if (t0 +      col > qr) sc[0][r] = -1e30f;
        if (t0 + 16 + col > qr) sc[1][r] = -1e30f;
        if (t0 + 32 + col > qr) sc[2][r] = -1e30f;
        if (t0 + 48 + col > qr) sc[3][r] = -1e30f;
      }
      float mx = fmaxf(fmaxf(sc[0][r], sc[1][r]), fmaxf(sc[2][r], sc[3][r]));
      mx = fmaxf(mx, __shfl_xor(mx, 1, 64));
      mx = fmaxf(mx, __shfl_xor(mx, 2, 64));
      mx = fmaxf(mx, __shfl_xor(mx, 4, 64));
      mx = fmaxf(mx, __shfl_xor(mx, 8, 64));
      mxr[r] = mx;
      needmax = fmaxf(needmax, mx - mi[r]);
    }
    // ---- defer-max: only rescale when the running max grows past THR=8
    if (!__all(needmax <= 8.0f)) {
      float alr[4];
#pragma unroll
      for (int r = 0; r < 4; r++) {
        float mn = fmaxf(mi[r], mxr[r]);
        float al = exp2f((mi[r] - mn)*L2E);
        mi[r] = mn; li[r] *= al; alr[r] = al;
      }
#pragma unroll
      for (int db = 0; db < 4; db++)
#pragma unroll
        for (int r = 0; r < 4; r++) oacc[db][r] *= alr[r];
    }
    // ---- P = exp2((s - mi)*L2E), pack bf16 (HW cvt_pk), lane-partial li
#pragma unroll
    for (int r = 0; r < 4; r++) {
      const float nb = -mi[r]*L2E;
      float p0 = exp2f(fmaf(sc[0][r], L2E, nb));
      float p1 = exp2f(fmaf(sc[1][r], L2E, nb));
      float p2 = exp2f(fmaf(sc[2][r], L2E, nb));
      float p3 = exp2f(fmaf(sc[3][r], L2E, nb));
      unsigned int pk01 = cvtpk(p0, p1);
      unsigned int pk23 = cvtpk(p2, p3);
      const int rw = (quad*4 + r)*72;
      sPw[rw + col]      = (u16)pk01;
      sPw[rw + 16 + col] = (u16)(pk01 >> 16);
      sPw[rw + 32 + col] = (u16)pk23;
      sPw[rw + 48 + col] = (u16)(pk23 >> 16);
      // li from ROUNDED p (matches bf16 PV numerator); reduce deferred.
      li[r] += (u2f(pk01 << 16) + u2f(pk01 & 0xffff0000u))
             + (u2f(pk23 << 16) + u2f(pk23 & 0xffff0000u));
    }
    // ---- PV (same-wave LDS write->read: DS pipe in-order per wave)
    bf16x8 pa0 = *(const bf16x8*)&sPw[col*72 + quad*8];
    bf16x8 pa1 = *(const bf16x8*)&sPw[col*72 + 32 + quad*8];
    __builtin_amdgcn_s_setprio(1);
#pragma unroll
    for (int db = 0; db < 4; db++) {
      const int vs = (db*16 + col)*32 + xorv*8;
      bf16x8 vb0 = *(const bf16x8*)&sV[cur][0][vs];
      bf16x8 vb1 = *(const bf16x8*)&sV[cur][1][vs];
      oacc[db] = __builtin_amdgcn_mfma_f32_16x16x32_bf16(pa0, vb0, oacc[db], 0,0,0);
      oacc[db] = __builtin_amdgcn_mfma_f32_16x16x32_bf16(pa1, vb1, oacc[db], 0,0,0);
    }
    __builtin_amdgcn_s_setprio(0);

    if (more) {                           // write next K tile (compiler waits loads)
      *(bf16x8*)&sK[nxt][krow*72 + kch*8]     = ka;
      *(bf16x8*)&sK[nxt][krow*72 + kch*8 + 8] = kb;
    }
    __syncthreads();                      // drains gld16 + ds_writes; flips buffers
  }

  // -------- epilogue: reduce lane-partial li across the 16-lane row group
  float inv[4];
#pragma unroll
  for (int r = 0; r < 4; r++) {
    float s = li[r];
    s += __shfl_xor(s, 1, 64);
    s += __shfl_xor(s, 2, 64);
    s += __shfl_xor(s, 4, 64);
    s += __shfl_xor(s, 8, 64);
    inv[r] = 1.0f / s;
  }
#pragma unroll
  for (int db = 0; db < 4; db++)
#pragma unroll
    for (int r = 0; r < 4; r++)
      O[base + (size_t)(q0 + w*16 + quad*4 + r)*Dd + db*16 + col] =
          f2bf(oacc[db][r] * inv[r]);
}

extern "C" void kernel_launch(void* const* d_in, const int* in_sizes, int n_in,
                              void* d_out, int out_size, void* d_ws, size_t ws_size,
                              hipStream_t stream) {
  const void* x  = d_in[0];
  const void* wq = d_in[1];
  const void* wk = d_in[2];
  const void* wv = d_in[3];
  const void* wo = d_in[4];
  // d_in[5] = mask: causal tril, hardcoded in attn kernel.

  const size_t T  = (size_t)Bb*Ss*Dd;   // 4,194,304
  const size_t WN = (size_t)Dd*Dd;      // 1,048,576

  char* ws = (char*)d_ws;
  unsigned int* flag = (unsigned int*)ws;
  u16* xb  = (u16*)(ws + 256);
  u16* wqb = xb  + T;
  u16* wkb = wqb + WN;
  u16* wvb = wkb + WN;
  u16* wob = wvb + WN;
  u16* Qb  = wob + WN;
  u16* Kb  = Qb + T;
  u16* Vb  = Kb + T;                    // holds V^T per head: [b][h][64][S]
  u16* AO  = Vb + T;                    // total ws use ~48.25 MB

  sniff<<<1, 1024, 0, stream>>>((const unsigned int*)x, flag, 65536);
  convert<<<dim3((int)(T/2048)),  256, 0, stream>>>(flag, x,  xb,  (int)T);
  convert<<<dim3((int)(WN/2048)), 256, 0, stream>>>(flag, wq, wqb, (int)WN);
  convert<<<dim3((int)(WN/2048)), 256, 0, stream>>>(flag, wk, wkb, (int)WN);
  convert<<<dim3((int)(WN/2048)), 256, 0, stream>>>(flag, wv, wvb, (int)WN);
  convert<<<dim3((int)(WN/2048)), 256, 0, stream>>>(flag, wo, wob, (int)WN);

  gemm_bt<<<dim3(8, 32, 3), 256, 0, stream>>>(xb, wqb, wkb, wvb, Qb, Kb, Vb,
                                              4096, 1024, 1024, flag, 0, 1);
  rmsrope<<<dim3((Bb*Ss*Hh)/4, 2), 256, 0, stream>>>(Qb, Kb);
  attn<<<dim3(32, 32), 256, 0, stream>>>(Qb, Kb, Vb, AO);
  gemm_bt<<<dim3(8, 32, 1), 256, 0, stream>>>(AO, wob, wob, wob, d_out, d_out, d_out,
                                              4096, 1024, 1024, flag, 1, 0);
}

// Round 5
// 265.507 us; speedup vs baseline: 2.8550x; 1.1080x over previous
//
#include <hip/hip_runtime.h>
#include <hip/hip_bf16.h>

#define Bb 2
#define Ss 2048
#define Dd 1024
#define Hh 16
#define Tt ((size_t)Bb*Ss*Dd)   // 4,194,304
#define WNn ((size_t)Dd*Dd)     // 1,048,576

typedef short bf16x8 __attribute__((ext_vector_type(8)));
typedef short bf16x4 __attribute__((ext_vector_type(4)));
typedef float floatx4 __attribute__((ext_vector_type(4)));
typedef unsigned short u16;

__device__ inline void gld16(void* lds, const void* g) {
  __builtin_amdgcn_global_load_lds(
      (const __attribute__((address_space(1))) unsigned int*)g,
      (__attribute__((address_space(3))) unsigned int*)lds, 16, 0, 0);
}

__device__ inline float bf2f(u16 u) {
  unsigned int x = ((unsigned int)u) << 16;
  float f; __builtin_memcpy(&f, &x, 4); return f;
}
__device__ inline u16 f2bf(float f) {
  unsigned int x; __builtin_memcpy(&x, &f, 4);
  x = (x + 0x7fff + ((x >> 16) & 1)) >> 16;   // RNE
  return (u16)x;
}
__device__ inline float u2f(unsigned int x) {
  float f; __builtin_memcpy(&f, &x, 4); return f;
}
// HW packed f32->bf16 (RNE), no builtin on gfx950 -> inline asm.
__device__ inline unsigned int cvtpk(float lo, float hi) {
  unsigned int r;
  asm("v_cvt_pk_bf16_f32 %0, %1, %2" : "=v"(r) : "v"(lo), "v"(hi));
  return r;
}

// ---------------- dtype sniffer (FALLBACK ONLY; host normally resolves dtype
// from in_sizes). finite bf16 never has exponent 0xFF; f32 read as u16 pairs
// has ~1/256 exponent-0xFF in the mantissa half.
__global__ void sniff(const unsigned int* __restrict__ x, unsigned int* __restrict__ flag,
                      int nwords) {
  __shared__ int cnt;
  if (threadIdx.x == 0) cnt = 0;
  __syncthreads();
  int local = 0;
  for (int i = threadIdx.x; i < nwords; i += blockDim.x) {
    unsigned int wd = x[i];
    if (((wd >> 7)  & 0xFFu) == 0xFFu) local++;
    if (((wd >> 23) & 0xFFu) == 0xFFu) local++;
  }
  atomicAdd(&cnt, local);
  __syncthreads();
  if (threadIdx.x == 0) *flag = (cnt >= 64) ? 1u : 0u;
}

// ---------------- normalize ALL input tensors to bf16 in one launch.
// dst buffers are contiguous in ws (xb|wq|wk|wv|wo). Block-uniform segment
// pick: x = blocks [0,2048), then 512 blocks per weight. smode: 1=f32 input,
// 0=bf16 input, -1=read runtime flag (sniff fallback).
__global__ __launch_bounds__(256) void convert_all(
    const void* __restrict__ x,  const void* __restrict__ wq,
    const void* __restrict__ wk, const void* __restrict__ wv,
    const void* __restrict__ wo, u16* __restrict__ dst,
    int smode, const unsigned int* __restrict__ flag) {
  const int gb = blockIdx.x;
  const void* src; size_t base; int lb;
  if (gb < 2048)      { src = x;  base = 0;            lb = gb;        }
  else if (gb < 2560) { src = wq; base = Tt;           lb = gb - 2048; }
  else if (gb < 3072) { src = wk; base = Tt + WNn;     lb = gb - 2560; }
  else if (gb < 3584) { src = wv; base = Tt + 2*WNn;   lb = gb - 3072; }
  else                { src = wo; base = Tt + 3*WNn;   lb = gb - 3584; }
  const size_t off = (size_t)lb*2048 + threadIdx.x*8;
  const bool f32 = (smode >= 0) ? (smode == 1) : (*flag != 0u);
  bf16x8 v;
  if (f32) {
    const float* s = (const float*)src + off;
#pragma unroll
    for (int j = 0; j < 8; j++) v[j] = (short)f2bf(s[j]);
  } else {
    v = *(const bf16x8*)((const u16*)src + off);
  }
  *(bf16x8*)(dst + base + off) = v;
}

// ---------------- GEMM: C = A(MxK) * W^T, W stored (N,K) row-major.
// m97 structure: 128x128 tile, BK=32, global_load_lds width=16.
// mode 0 (QKV projection): blockIdx.z 0/1 -> fused RMSNorm+RoPE epilogue
//   (each wave holds one full 64-dim head for 64 rows; Q also pre-scaled by
//   1/sqrt(DH)=0.125, exact in bf16); z=2 -> V written transposed per head
//   Vt[b][h][dl][s] so attn reads V^T rows directly.
// mode 1 (output projection): plain store; f32 out iff input was f32
//   (outMode 1=f32, 0=bf16, -1=runtime flag).
__global__ __launch_bounds__(256) void gemm_bt(
    const u16* __restrict__ A,
    const u16* __restrict__ W0, const u16* __restrict__ W1, const u16* __restrict__ W2,
    void* __restrict__ C0, void* __restrict__ C1, void* __restrict__ C2,
    int M, int N, int K, const unsigned int* __restrict__ flag, int outMode, int mode)
{
  const u16* W; void* C;
  if (blockIdx.z == 0)      { W = W0; C = C0; }
  else if (blockIdx.z == 1) { W = W1; C = C1; }
  else                      { W = W2; C = C2; }

  __shared__ __align__(16) u16 sA[128*32];
  __shared__ __align__(16) u16 sB[128*32];

  const int tid  = threadIdx.x;
  const int lane = tid & 63;
  const int w    = tid >> 6;
  const int wm = w >> 1, wn = w & 1;
  const int col = lane & 15, quad = lane >> 4;
  const int bm = blockIdx.y, bn = blockIdx.x;

  floatx4 acc[4][4] = {};

  const int c0 = tid, c1 = tid + 256;
  const size_t aOff0 = (size_t)(bm*128 + (c0 >> 2))*K + (c0 & 3)*8;
  const size_t aOff1 = (size_t)(bm*128 + (c1 >> 2))*K + (c1 & 3)*8;
  const size_t bOff0 = (size_t)(bn*128 + (c0 >> 2))*K + (c0 & 3)*8;
  const size_t bOff1 = (size_t)(bn*128 + (c1 >> 2))*K + (c1 & 3)*8;

  for (int kk = 0; kk < K; kk += 32) {
    gld16(&sA[c0*8], A + aOff0 + kk);
    gld16(&sA[c1*8], A + aOff1 + kk);
    gld16(&sB[c0*8], W + bOff0 + kk);
    gld16(&sB[c1*8], W + bOff1 + kk);
    __syncthreads();
    bf16x8 af[4], bfr[4];
#pragma unroll
    for (int i = 0; i < 4; i++)
      af[i] = *(const bf16x8*)&sA[(wm*64 + i*16 + col)*32 + quad*8];
#pragma unroll
    for (int j = 0; j < 4; j++)
      bfr[j] = *(const bf16x8*)&sB[(wn*64 + j*16 + col)*32 + quad*8];
#pragma unroll
    for (int i = 0; i < 4; i++)
#pragma unroll
      for (int j = 0; j < 4; j++)
        acc[i][j] = __builtin_amdgcn_mfma_f32_16x16x32_bf16(af[i], bfr[j], acc[i][j], 0, 0, 0);
    __syncthreads();
  }

  if (mode == 0 && blockIdx.z == 2) {
    // V: transposed epilogue. d = gcol (head h = d>>6, dl = d&63), s = grow
    // & 2047, b = grow>>11. Four consecutive rows (r) s-contiguous -> bf16x4.
    u16* Ct = (u16*)C;
#pragma unroll
    for (int i = 0; i < 4; i++)
#pragma unroll
      for (int j = 0; j < 4; j++) {
        int d = bn*128 + wn*64 + j*16 + col;
        int g = bm*128 + wm*64 + i*16 + quad*4;
        int hh = d >> 6, dl = d & 63;
        int bb = g >> 11, s = g & (Ss - 1);
        bf16x4 pk;
#pragma unroll
        for (int r = 0; r < 4; r++) pk[r] = (short)f2bf(acc[i][j][r]);
        *(bf16x4*)&Ct[((size_t)(bb*Hh + hh)*64 + dl)*Ss + s] = pk;
      }
  } else if (mode == 0) {
    // Q/K: fused RMSNorm (over the 64-dim head = this wave's 64 cols) + RoPE.
    // Row owner lanes = same quad, 16 cols; RoPE pair (d, d+32) = (j, j+2)
    // in the same lane. Only j=0 rotates (freq idx = col < 16); j=1/3 pass
    // through (zero-freq tail). Q pre-scaled by 0.125 (pow2, exact in bf16).
    const float qs = (blockIdx.z == 0) ? 0.125f : 1.0f;
    const float freq = exp2f((-10.0f/15.0f) * (float)col);   // 1024^(-col/15)
    u16* Co = (u16*)C;
    const size_t cb = (size_t)(bn*128 + wn*64 + col);
#pragma unroll
    for (int i = 0; i < 4; i++)
#pragma unroll
      for (int r = 0; r < 4; r++) {
        float ss = 0.0f;
#pragma unroll
        for (int j = 0; j < 4; j++) ss += acc[i][j][r]*acc[i][j][r];
        ss += __shfl_xor(ss, 1, 64);
        ss += __shfl_xor(ss, 2, 64);
        ss += __shfl_xor(ss, 4, 64);
        ss += __shfl_xor(ss, 8, 64);
        float rn = rsqrtf(ss*(1.0f/64.0f) + 1e-6f) * qs;
        int grow = bm*128 + wm*64 + i*16 + quad*4 + r;
        float th = (float)(grow & (Ss - 1)) * freq;
        float c = cosf(th), sn = sinf(th);
        float x0 = acc[i][0][r]*rn, x1 = acc[i][1][r]*rn;
        float x2 = acc[i][2][r]*rn, x3 = acc[i][3][r]*rn;
        size_t rowb = (size_t)grow*N + cb;
        Co[rowb]      = f2bf(x0*c + x2*sn);
        Co[rowb + 16] = f2bf(x1);
        Co[rowb + 32] = f2bf(x2*c - x0*sn);
        Co[rowb + 48] = f2bf(x3);
      }
  } else {
    const bool f32o = (outMode == 1) || (outMode == -1 && *flag != 0u);
#pragma unroll
    for (int i = 0; i < 4; i++)
#pragma unroll
      for (int j = 0; j < 4; j++)
#pragma unroll
        for (int r = 0; r < 4; r++) {
          int grow = bm*128 + wm*64 + i*16 + quad*4 + r;
          int gcol = bn*128 + wn*64 + j*16 + col;
          size_t idx = (size_t)grow*N + gcol;
          float v = acc[i][j][r];
          if (f32o) ((float*)C)[idx] = v;
          else      ((u16*)C)[idx]   = f2bf(v);
        }
  }
}

// ---------------- Causal flash attention, heavy-first + double-buffered.
// Grid (32 bh, 32 qy): qt = 31 - blockIdx.y so linear dispatch order is
// descending work (heavy q-tiles start first; light blocks backfill) -> 1024
// blocks, 3 resident/CU (LDS-capped at 44KB). K/V double-buffered with loads
// issued before compute. sV staged via gld16 with a pre-swizzled global
// source; PV read applies the same XOR. Online softmax: defer-max (THR=8) +
// lane-partial li (row-reduced once at epilogue).
__global__ __launch_bounds__(256) void attn(
    const u16* __restrict__ Q, const u16* __restrict__ Kv,
    const u16* __restrict__ Vt, u16* __restrict__ O)
{
  __shared__ __align__(16) u16 sK[2][64*72];      // [buf][t][dh], stride 72
  __shared__ __align__(16) u16 sV[2][2][64*32];   // [buf][ts][slot], gld16-linear
  __shared__ __align__(16) u16 sP[4][16*72];      // per-wave P [q][t], stride 72

  const int tid  = threadIdx.x;
  const int lane = tid & 63;
  const int w    = tid >> 6;
  const int col = lane & 15, quad = lane >> 4;
  const int bh = blockIdx.x;
  const int qt = 31 - (int)blockIdx.y;            // heavy-first dispatch order
  const int b = bh >> 4, h = bh & 15;
  const size_t base  = (size_t)b*Ss*Dd + (size_t)h*64;
  const size_t vbase = (size_t)bh*64*Ss;

  const int krow = tid >> 2;              // K stage: row 0..63
  const int kch  = (tid & 3) * 2;         // 16B-chunk col {0,2,4,6}
  const int vrow = tid >> 2;
  const int vcp  = (tid & 3) ^ (vrow & 3) ^ ((vrow >> 2) & 3);
  const u16* Vh = Vt + vbase + (size_t)vrow*Ss + vcp*8;
  const int xorv = quad ^ (col & 3) ^ ((col >> 2) & 3);  // PV read swizzle
  u16* sPw = &sP[w][0];
  const float L2E = 1.44269504f;

  const int q0 = qt * 64;
  const int nk = qt + 1;                  // 64-t tiles
  const int qmin = q0 + w*16;

  bf16x8 qf0, qf1;
  {
    const size_t qoff = base + (size_t)(q0 + w*16 + col)*Dd + quad*8;
    qf0 = *(const bf16x8*)(Q + qoff);
    qf1 = *(const bf16x8*)(Q + qoff + 32);
  }
  floatx4 oacc[4] = {};
  float mi[4], li[4];
#pragma unroll
  for (int r = 0; r < 4; r++) { mi[r] = -1e30f; li[r] = 0.0f; }

  // -------- prologue: stage tile 0 into buffer 0
  {
    const u16* kg = Kv + base + (size_t)krow*Dd + kch*8;
    bf16x8 ka = *(const bf16x8*)kg;
    bf16x8 kb = *(const bf16x8*)(kg + 8);
    gld16(&sV[0][0][tid*8], Vh);
    gld16(&sV[0][1][tid*8], Vh + 32);
    *(bf16x8*)&sK[0][krow*72 + kch*8]     = ka;
    *(bf16x8*)&sK[0][krow*72 + kch*8 + 8] = kb;
    __syncthreads();                      // drains gld16 + ds_writes
  }

  for (int kt = 0; kt < nk; kt++) {
    const int t0 = kt*64;
    const int cur = kt & 1, nxt = cur ^ 1;
    const bool more = (kt + 1 < nk);
    bf16x8 ka, kb;
    if (more) {                           // issue next-tile loads early
      const u16* kg = Kv + base + (size_t)(t0 + 64 + krow)*Dd + kch*8;
      ka = *(const bf16x8*)kg;
      kb = *(const bf16x8*)(kg + 8);
      gld16(&sV[nxt][0][tid*8], Vh + t0 + 64);
      gld16(&sV[nxt][1][tid*8], Vh + t0 + 96);
    }

    // ---- QK^T (4 t-subtiles x 2 k-halves); Q pre-scaled -> sc is the score
    floatx4 sc[4] = {};
    __builtin_amdgcn_s_setprio(1);
#pragma unroll
    for (int ts = 0; ts < 4; ts++) {
      bf16x8 k0 = *(const bf16x8*)&sK[cur][(ts*16 + col)*72 + quad*8];
      bf16x8 k1 = *(const bf16x8*)&sK[cur][(ts*16 + col)*72 + 32 + quad*8];
      sc[ts] = __builtin_amdgcn_mfma_f32_16x16x32_bf16(qf0, k0, sc[ts], 0,0,0);
      sc[ts] = __builtin_amdgcn_mfma_f32_16x16x32_bf16(qf1, k1, sc[ts], 0,0,0);
    }
    __builtin_amdgcn_s_setprio(0);

    // ---- mask (boundary tile only) + row max
    const bool boundary = (t0 + 63 > qmin);
    float mxr[4];
    float needmax = 0.0f;
#pragma unroll
    for (int r = 0; r < 4; r++) {
      if (boundary) {
        const int qr = q0 + w*16 + quad*4 + r;
        if (t0 +      col > qr) sc[0][r] = -1e30f;
        if (t0 + 16 + col > qr) sc[1][r] = -1e30f;
        if (t0 + 32 + col > qr) sc[2][r] = -1e30f;
        if (t0 + 48 + col > qr) sc[3][r] = -1e30f;
      }
      float mx = fmaxf(fmaxf(sc[0][r], sc[1][r]), fmaxf(sc[2][r], sc[3][r]));
      mx = fmaxf(mx, __shfl_xor(mx, 1, 64));
      mx = fmaxf(mx, __shfl_xor(mx, 2, 64));
      mx = fmaxf(mx, __shfl_xor(mx, 4, 64));
      mx = fmaxf(mx, __shfl_xor(mx, 8, 64));
      mxr[r] = mx;
      needmax = fmaxf(needmax, mx - mi[r]);
    }
    // ---- defer-max: only rescale when the running max grows past THR=8
    if (!__all(needmax <= 8.0f)) {
      float alr[4];
#pragma unroll
      for (int r = 0; r < 4; r++) {
        float mn = fmaxf(mi[r], mxr[r]);
        float al = exp2f((mi[r] - mn)*L2E);
        mi[r] = mn; li[r] *= al; alr[r] = al;
      }
#pragma unroll
      for (int db = 0; db < 4; db++)
#pragma unroll
        for (int r = 0; r < 4; r++) oacc[db][r] *= alr[r];
    }
    // ---- P = exp2((s - mi)*L2E), pack bf16 (HW cvt_pk), lane-partial li
#pragma unroll
    for (int r = 0; r < 4; r++) {
      const float nb = -mi[r]*L2E;
      float p0 = exp2f(fmaf(sc[0][r], L2E, nb));
      float p1 = exp2f(fmaf(sc[1][r], L2E, nb));
      float p2 = exp2f(fmaf(sc[2][r], L2E, nb));
      float p3 = exp2f(fmaf(sc[3][r], L2E, nb));
      unsigned int pk01 = cvtpk(p0, p1);
      unsigned int pk23 = cvtpk(p2, p3);
      const int rw = (quad*4 + r)*72;
      sPw[rw + col]      = (u16)pk01;
      sPw[rw + 16 + col] = (u16)(pk01 >> 16);
      sPw[rw + 32 + col] = (u16)pk23;
      sPw[rw + 48 + col] = (u16)(pk23 >> 16);
      // li from ROUNDED p (matches bf16 PV numerator); reduce deferred.
      li[r] += (u2f(pk01 << 16) + u2f(pk01 & 0xffff0000u))
             + (u2f(pk23 << 16) + u2f(pk23 & 0xffff0000u));
    }
    // ---- PV (same-wave LDS write->read: DS pipe in-order per wave)
    bf16x8 pa0 = *(const bf16x8*)&sPw[col*72 + quad*8];
    bf16x8 pa1 = *(const bf16x8*)&sPw[col*72 + 32 + quad*8];
    __builtin_amdgcn_s_setprio(1);
#pragma unroll
    for (int db = 0; db < 4; db++) {
      const int vs = (db*16 + col)*32 + xorv*8;
      bf16x8 vb0 = *(const bf16x8*)&sV[cur][0][vs];
      bf16x8 vb1 = *(const bf16x8*)&sV[cur][1][vs];
      oacc[db] = __builtin_amdgcn_mfma_f32_16x16x32_bf16(pa0, vb0, oacc[db], 0,0,0);
      oacc[db] = __builtin_amdgcn_mfma_f32_16x16x32_bf16(pa1, vb1, oacc[db], 0,0,0);
    }
    __builtin_amdgcn_s_setprio(0);

    if (more) {                           // write next K tile (compiler waits loads)
      *(bf16x8*)&sK[nxt][krow*72 + kch*8]     = ka;
      *(bf16x8*)&sK[nxt][krow*72 + kch*8 + 8] = kb;
    }
    __syncthreads();                      // drains gld16 + ds_writes; flips buffers
  }

  // -------- epilogue: reduce lane-partial li across the 16-lane row group
  float inv[4];
#pragma unroll
  for (int r = 0; r < 4; r++) {
    float s = li[r];
    s += __shfl_xor(s, 1, 64);
    s += __shfl_xor(s, 2, 64);
    s += __shfl_xor(s, 4, 64);
    s += __shfl_xor(s, 8, 64);
    inv[r] = 1.0f / s;
  }
#pragma unroll
  for (int db = 0; db < 4; db++)
#pragma unroll
    for (int r = 0; r < 4; r++)
      O[base + (size_t)(q0 + w*16 + quad*4 + r)*Dd + db*16 + col] =
          f2bf(oacc[db][r] * inv[r]);
}

extern "C" void kernel_launch(void* const* d_in, const int* in_sizes, int n_in,
                              void* d_out, int out_size, void* d_ws, size_t ws_size,
                              hipStream_t stream) {
  const void* x  = d_in[0];
  const void* wq = d_in[1];
  const void* wk = d_in[2];
  const void* wv = d_in[3];
  const void* wo = d_in[4];
  // d_in[5] = mask: causal tril, hardcoded in attn kernel.

  const size_t T  = Tt;
  const size_t WN = WNn;

  char* ws = (char*)d_ws;
  unsigned int* flag = (unsigned int*)ws;
  u16* xb  = (u16*)(ws + 256);
  u16* wqb = xb  + T;
  u16* wkb = wqb + WN;
  u16* wvb = wkb + WN;
  u16* wob = wvb + WN;
  u16* Qb  = wob + WN;
  u16* Kb  = Qb + T;
  u16* Vb  = Kb + T;                    // holds V^T per head: [b][h][64][S]
  u16* AO  = Vb + T;                    // total ws use ~48.25 MB

  // Resolve input dtype on the HOST from byte sizes (f32 = 16MB, bf16 = 8MB).
  // smode: 1 = f32, 0 = bf16, -1 = unknown -> runtime sniff fallback.
  int smode = -1;
  if (in_sizes && n_in > 0) {
    if (in_sizes[0] == (int)(T*4))      smode = 1;
    else if (in_sizes[0] == (int)(T*2)) smode = 0;
  }
  if (smode < 0)
    sniff<<<1, 1024, 0, stream>>>((const unsigned int*)x, flag, 65536);

  convert_all<<<4096, 256, 0, stream>>>(x, wq, wk, wv, wo, xb, smode, flag);

  // QKV projection with fused RMSNorm+RoPE (Q,K) and V-transpose epilogues.
  gemm_bt<<<dim3(8, 32, 3), 256, 0, stream>>>(xb, wqb, wkb, wvb, Qb, Kb, Vb,
                                              4096, 1024, 1024, flag, 0, 0);
  attn<<<dim3(32, 32), 256, 0, stream>>>(Qb, Kb, Vb, AO);
  // Output projection; out dtype follows input dtype.
  gemm_bt<<<dim3(8, 32, 1), 256, 0, stream>>>(AO, wob, wob, wob, d_out, d_out, d_out,
                                              4096, 1024, 1024, flag, smode, 1);
}